// Round 2
// baseline (634.432 us; speedup 1.0000x reference)
//
#include <hip/hip_runtime.h>

// Problem constants
#define BB    16
#define CIN   32
#define LEN   1024
#define TT    64
#define COUT  64
#define KK    3

// Tiling
#define TL       16                  // l per block -> 64x16 = 1024 blocks (4/CU, grid-capped)
#define HALO     (TL + 2)            // 18 rows incl. conv halo
#define TCH      8                   // t per stage -> 8 stages, double-buffered
#define NTHREADS 256                 // 4 waves; thread = (co-group[4b], l[4b])
#define CO_PER   4                   // co per thread (16 groups x 4 = 64)
#define GPR      2                   // 16-B granules per row per stage (8 t = 32 B)
#define NGRAN    (CIN * HALO * GPR)  // 1152 granules per buffer (18432 B)
#define ROUNDS   (NGRAN / 64)        // 18 wave-rounds per stage

// INVARIANT (bit-exact vs np ref, proven in earlier rounds): per output cell
// the conv sum is ONE sequential fmaf chain, k outer (0..2), ci inner (0..31),
// acc=0; LIF fp32: s=pot+a; p=s*0.9f; spk=(p>=0.25f); pot=spk?0:p.

// Packed weights: wpk[(g*3+k)*32+ci] = {w[g*4+0][ci][k], ..., w[g*4+3][ci][k]}
__device__ float4 wpk[16 * 3 * 32];
// Zero page for out-of-range halo rows (never written -> stays 0).
__device__ float  zeros_g[64];

__global__ void repack_w(const float* __restrict__ w) {
    const int i = blockIdx.x * 256 + threadIdx.x;
    if (i < 16 * 3 * 32) {
        const int g  = i / 96;
        const int k  = (i % 96) / 32;
        const int ci = i % 32;
        float4 v;
        v.x = w[((g * 4 + 0) * CIN + ci) * KK + k];
        v.y = w[((g * 4 + 1) * CIN + ci) * KK + k];
        v.z = w[((g * 4 + 2) * CIN + ci) * KK + k];
        v.w = w[((g * 4 + 3) * CIN + ci) * KK + k];
        wpk[i] = v;
    }
}

// 16-B async global->LDS (dest = uniform base + lane*16; source per-lane).
#define GLD16(GP, LP) __builtin_amdgcn_global_load_lds(                      \
    (const __attribute__((address_space(1))) void*)(GP),                     \
    (__attribute__((address_space(3))) void*)(LP), 16, 0, 0)

__global__ __launch_bounds__(NTHREADS, 4)
void snn_v5(const float* __restrict__ x, float* __restrict__ out) {
    // double-buffered stage tile; granule slot (ci,row,h') holds source h =
    // h' ^ ((row>>2)&1)  -> read bank-starts hit 8 distinct slots (2-way).
    __shared__ float4 xs[2][NGRAN];          // 36864 B total

    const int tid  = threadIdx.x;
    const int l    = tid & (TL - 1);
    const int g    = tid >> 4;               // 0..15 co-group
    const int co0  = g * CO_PER;
    const int lane = tid & 63;
    const int wv   = __builtin_amdgcn_readfirstlane(tid >> 6);   // 0..3
    const int l0   = blockIdx.x * TL;
    const int b    = blockIdx.y;

    const float* xb = x + (size_t)b * CIN * LEN * TT;

    // per-lane staging source pointers (pre-swizzled global addresses so the
    // linear global_load_lds destination realizes the swizzled LDS layout)
    auto mk_src = [&](int rb) -> const float* {
        const int G   = rb * 64 + lane;      // LDS granule this lane fills
        const int ci  = G / 36;
        const int rem = G - ci * 36;
        const int row = rem >> 1;
        const int h   = (rem & 1) ^ ((row >> 2) & 1);   // inverse swizzle
        const int lg  = l0 - 1 + row;
        return (lg >= 0 && lg < LEN)
             ? xb + ((size_t)ci * LEN + lg) * TT + h * 4
             : zeros_g;
    };
    const float* s0 = mk_src(wv);
    const float* s1 = mk_src(wv + 4);
    const float* s2 = mk_src(wv + 8);
    const float* s3 = mk_src(wv + 12);
    const float* s4 = (wv < 2) ? mk_src(wv + 16) : zeros_g;

    auto issue = [&](int sc, int buf) {
        char* lb = (char*)&xs[buf][0];
        GLD16(s0 + sc * TCH, lb + (wv +  0) * 1024);
        GLD16(s1 + sc * TCH, lb + (wv +  4) * 1024);
        GLD16(s2 + sc * TCH, lb + (wv +  8) * 1024);
        GLD16(s3 + sc * TCH, lb + (wv + 12) * 1024);
        if (wv < 2)
            GLD16(s4 + sc * TCH, lb + (wv + 16) * 1024);
    };

    float    pot[CO_PER] = {0.f, 0.f, 0.f, 0.f};
    unsigned mlo[CO_PER] = {0u, 0u, 0u, 0u};     // spike bits t=0..31
    unsigned mhi[CO_PER] = {0u, 0u, 0u, 0u};     // spike bits t=32..63

    issue(0, 0);                                 // prologue: stage 0 -> buf 0

    for (int sc = 0; sc < TT / TCH; ++sc) {
        const int cur = sc & 1;
        // barrier: (a) drains our global_load_lds -> buf[cur] ready for all;
        // (b) all waves finished reading buf[cur^1] -> safe to refill it.
        __syncthreads();
        if (sc + 1 < TT / TCH) issue(sc + 1, cur ^ 1);

        const float4* __restrict__ xsv = xs[cur];

        // ---- conv: EXACT chain order k outer, ci inner, sequential fmaf
        float acc[CO_PER][TCH];
        #pragma unroll
        for (int j = 0; j < CO_PER; ++j)
            #pragma unroll
            for (int i = 0; i < TCH; ++i) acc[j][i] = 0.0f;

        #pragma unroll
        for (int k = 0; k < KK; ++k) {
            const int row = l + k;
            const int sw  = (row >> 2) & 1;
            const int gA  = row * 2 + sw;          // holds source h=0 (t 0-3)
            const int gB  = row * 2 + (1 ^ sw);    // holds source h=1 (t 4-7)
            const float4* wk = wpk + (g * 3 + k) * 32;
            #pragma unroll 2
            for (int cic = 0; cic < CIN / 4; ++cic) {
                #pragma unroll
                for (int c4 = 0; c4 < 4; ++c4) {
                    const int ci = cic * 4 + c4;
                    const float4 xa  = xsv[ci * 36 + gA];
                    const float4 xc  = xsv[ci * 36 + gB];
                    const float4 wv4 = wk[ci];     // one dwordx4, L1-resident
                    #pragma unroll
                    for (int j = 0; j < CO_PER; ++j) {
                        const float wj = (j == 0) ? wv4.x : (j == 1) ? wv4.y
                                       : (j == 2) ? wv4.z : wv4.w;
                        acc[j][0] = fmaf(xa.x, wj, acc[j][0]);
                        acc[j][1] = fmaf(xa.y, wj, acc[j][1]);
                        acc[j][2] = fmaf(xa.z, wj, acc[j][2]);
                        acc[j][3] = fmaf(xa.w, wj, acc[j][3]);
                        acc[j][4] = fmaf(xc.x, wj, acc[j][4]);
                        acc[j][5] = fmaf(xc.y, wj, acc[j][5]);
                        acc[j][6] = fmaf(xc.z, wj, acc[j][6]);
                        acc[j][7] = fmaf(xc.w, wj, acc[j][7]);
                    }
                }
            }
        }

        // ---- LIF scan (t-sequential) -> spike bitmask accumulation
        const unsigned sh = (unsigned)((sc & 3) * TCH);
        #pragma unroll
        for (int j = 0; j < CO_PER; ++j) {
            unsigned sb = 0u;
            #pragma unroll
            for (int i = 0; i < TCH; ++i) {
                const float s  = pot[j] + acc[j][i];
                const float p  = s * 0.9f;
                const bool  sp = (p >= 0.25f);
                sb |= sp ? (1u << i) : 0u;
                pot[j] = sp ? 0.0f : p;
            }
            if (sc < 4) mlo[j] |= sb << sh;
            else        mhi[j] |= sb << sh;
        }
    }

    // ---- epilogue: expand bitmasks -> full 256-B contiguous rows per (co,l)
    float* outb = out + (size_t)b * COUT * LEN * TT;
    #pragma unroll
    for (int j = 0; j < CO_PER; ++j) {
        float* dst = outb + ((size_t)(co0 + j) * LEN + (l0 + l)) * TT;
        #pragma unroll
        for (int tq = 0; tq < 16; ++tq) {
            const unsigned word = (tq < 8) ? mlo[j] : mhi[j];
            const unsigned nib  = word >> ((tq & 7) * 4);
            float4 v;
            v.x = (nib & 1u) ? 1.0f : 0.0f;
            v.y = (nib & 2u) ? 1.0f : 0.0f;
            v.z = (nib & 4u) ? 1.0f : 0.0f;
            v.w = (nib & 8u) ? 1.0f : 0.0f;
            *(float4*)(dst + tq * 4) = v;
        }
    }
}

extern "C" void kernel_launch(void* const* d_in, const int* in_sizes, int n_in,
                              void* d_out, int out_size, void* d_ws, size_t ws_size,
                              hipStream_t stream) {
    const float* x = (const float*)d_in[0];   // (16, 32, 1024, 64) fp32
    const float* w = (const float*)d_in[1];   // (64, 32, 3) fp32
    float* out = (float*)d_out;               // (16, 64, 1024, 64) fp32
    (void)d_ws; (void)ws_size; (void)in_sizes; (void)n_in; (void)out_size;

    hipLaunchKernelGGL(repack_w, dim3(6), dim3(256), 0, stream, w);
    hipLaunchKernelGGL(snn_v5, dim3(LEN / TL, BB), dim3(NTHREADS),
                       0, stream, x, out);
}